// Round 5
// baseline (305.281 us; speedup 1.0000x reference)
//
#include <hip/hip_runtime.h>

// x:    (2, 768, 8,8,8)   -> (2,768,512)
// out:  (2, 48, 64,64,64) -> (2,48,262144)
// output: (2, 32, 64,64,64)
constexpr int NCLS = 32;

// ws float offsets
constexpr int WS_POOL = 64;     // 2*768
constexpr int WS_XF  = 1600;    // 2*256
constexpr int WS_PAR = 2112;    // 2*32*153 = 9792
constexpr int WS_P2  = 11904;   // 768 blocks * {sum,sumsq}

typedef float f2 __attribute__((ext_vector_type(2)));

__device__ __forceinline__ float wred(float v) {
#pragma unroll
  for (int off = 32; off > 0; off >>= 1) v += __shfl_down(v, off, 64);
  return v;
}

// packed fp32 helpers. NOTE (round-4 model): fp32 peak 157.3 TF = scalar rate;
// pk ops are issue-count-neutral on cycles. Kept for compactness/register pairing.
__device__ __forceinline__ f2 pfma(float w, f2 v, f2 a) {
  return __builtin_elementwise_fma((f2)w, v, a);
}
__device__ __forceinline__ f2 paff(f2 v, float sc, float sh) {
  return __builtin_elementwise_fma(v, (f2)sc, (f2)sh);
}
__device__ __forceinline__ f2 prelu(f2 a) {
  return __builtin_elementwise_max(a, (f2)0.f);
}

// K1: 800 blocks. Blocks 0..767: GN2 partial sums (32768 contiguous floats each).
//     Blocks 768..799: GN1 stats + relu-mean pool for one (b,group) (24576 floats).
__global__ void k1_stats(const float* __restrict__ x, const float* __restrict__ oin,
                         const float* __restrict__ g1, const float* __restrict__ b1,
                         float* __restrict__ ws) {
  int t = threadIdx.x;
  int wid = t >> 6, lane = t & 63;
  __shared__ float red[8];
  if (blockIdx.x < 768) {
    int blk = blockIdx.x;
    const float4* p = reinterpret_cast<const float4*>(oin + (size_t)blk * 32768);
    float s = 0.f, s2 = 0.f;
#pragma unroll
    for (int k = 0; k < 32; ++k) {
      float4 v = p[k * 256 + t];
      s  += v.x + v.y + v.z + v.w;
      s2 += v.x*v.x + v.y*v.y + v.z*v.z + v.w*v.w;
    }
    s = wred(s); s2 = wred(s2);
    if (lane == 0) { red[wid*2] = s; red[wid*2+1] = s2; }
    __syncthreads();
    if (t == 0) {
      ws[WS_P2 + blk*2]   = red[0]+red[2]+red[4]+red[6];
      ws[WS_P2 + blk*2+1] = red[1]+red[3]+red[5]+red[7];
    }
  } else {
    int g = blockIdx.x - 768;              // b = g>>4, grp = g&15
    __shared__ float mstat[2];
    const float4* p = reinterpret_cast<const float4*>(x + g * 24576);
    float s = 0.f, s2 = 0.f;
#pragma unroll
    for (int k = 0; k < 24; ++k) {
      float4 v = p[k * 256 + t];
      s  += v.x + v.y + v.z + v.w;
      s2 += v.x*v.x + v.y*v.y + v.z*v.z + v.w*v.w;
    }
    s = wred(s); s2 = wred(s2);
    if (lane == 0) { red[wid*2] = s; red[wid*2+1] = s2; }
    __syncthreads();
    if (t == 0) {
      float S  = red[0]+red[2]+red[4]+red[6];
      float S2 = red[1]+red[3]+red[5]+red[7];
      float mean = S * (1.f/24576.f);
      float var  = S2 * (1.f/24576.f) - mean*mean;
      mstat[0] = mean; mstat[1] = rsqrtf(var + 1e-5f);
    }
    __syncthreads();
    float mean = mstat[0], rstd = mstat[1];
#pragma unroll
    for (int k = 0; k < 12; ++k) {
      int i = k*4 + wid;                   // channel within group [0,48)
      int c = (g & 15) * 48 + i;           // channel [0,768)
      float sc = rstd * g1[c];
      float sh = b1[c] - mean * sc;
      const float* q = x + g * 24576 + i * 512;
      float acc = 0.f;
#pragma unroll
      for (int j = 0; j < 8; ++j)
        acc += fmaxf(fmaf(q[lane + j*64], sc, sh), 0.f);
      acc = wred(acc);
      if (lane == 0) ws[WS_POOL + (g >> 4) * 768 + c] = acc * (1.f/512.f);
    }
  }
}

// K2: x_feat, wave-per-output (coalesced row reads). 512 outputs -> 128 blocks.
__global__ void k2_xfeat(const float* __restrict__ gapw, const float* __restrict__ gapb,
                         float* __restrict__ ws) {
  int wid = threadIdx.x >> 6, lane = threadIdx.x & 63;
  int idx = blockIdx.x * 4 + wid;          // [0,512)
  int b = idx >> 8, o = idx & 255;
  const float* pw = gapw + o * 768;
  const float* pp = ws + WS_POOL + b * 768;
  float s = 0.f;
#pragma unroll
  for (int i = 0; i < 12; ++i) {
    int cc = lane + i*64;
    s += pw[cc] * pp[cc];
  }
  s = wred(s);
  if (lane == 0) ws[WS_XF + idx] = s + gapb[o];
}

// K3: params, wave-per-output (coalesced). 9792 outputs -> 2448 blocks.
__global__ void k3_params(const float* __restrict__ cw, const float* __restrict__ cb,
                          const float* __restrict__ te, float* __restrict__ ws) {
  int wid = threadIdx.x >> 6, lane = threadIdx.x & 63;
  int e = blockIdx.x * 4 + wid;            // [0,9792)
  int b = e / (NCLS * 153);
  int r = e % (NCLS * 153);
  int c = r / 153, p = r % 153;
  const float* w  = cw + p * 512;
  const float* xf = ws + WS_XF + b * 256;
  const float* tv = te + c * 256;
  float s = 0.f;
#pragma unroll
  for (int i = 0; i < 4; ++i) {
    int f = lane + i*64;
    s += w[f] * xf[f] + w[256 + f] * tv[f];
  }
  s = wred(s);
  if (lane == 0) ws[WS_PAR + e] = s + cb[p];
}

// K4: fused GN2-finalize + main head. v5:
//  Model (fit to rounds 0-4): dur ~ B(22us) + C * (wave,class) instances/CU;
//  C_smem ~ 570cyc (s_load wait chain, per-CU serialized; waves DON'T hide it),
//  C_lds ~ 1480cyc. => minimize instances on the SMEM path, zero duplication:
//  256 blocks x 256 thr; thread = 8 voxels (two float4 groups = 4 f2 pairs);
//  ALL 32 classes per block; weights via wave-uniform s_load. 128 inst/CU
//  (half of round 4). Single oin pass. 1 wave/SIMD is predicted harmless
//  (r0 vs r3: occupancy-invariant).
__global__ __launch_bounds__(256) void k4_main(const float* __restrict__ oin,
                                               const float* __restrict__ prew,
                                               const float* __restrict__ preb,
                                               const float* __restrict__ g2,
                                               const float* __restrict__ b2,
                                               const float* __restrict__ ws,
                                               float* __restrict__ out) {
  __shared__ __align__(16) float prewT[384];
  __shared__ float2 ssl[48];
  __shared__ float ms[64];
  int t = threadIdx.x;
  int b    = blockIdx.x >> 7;        // batch [0,2)
  int tile = blockIdx.x & 127;       // [0,128) -> 2048 voxels per tile

  if (t < 32) {
    float S = 0.f, S2 = 0.f;
#pragma unroll
    for (int k = 0; k < 24; ++k) {
      S  += ws[WS_P2 + (t*24 + k)*2];
      S2 += ws[WS_P2 + (t*24 + k)*2 + 1];
    }
    float mean = S * (1.f/786432.f);
    float var  = S2 * (1.f/786432.f) - mean*mean;
    ms[t*2] = mean; ms[t*2+1] = rsqrtf(var + 1e-5f);
  }
  if (t < 128) {
#pragma unroll
    for (int k = 0; k < 3; ++k) {
      int i = t + k*128;
      prewT[(i % 48) * 8 + (i / 48)] = prew[i];
    }
  }
  __syncthreads();
  if (t < 48) {
    int grp = (b << 4) + t / 3;
    float mean = ms[grp*2], rstd = ms[grp*2+1];
    float sc = rstd * g2[t];
    ssl[t] = make_float2(sc, b2[t] - mean * sc);
  }
  __syncthreads();

  // h0 for 8 voxels: two float4 groups (at +0 and +256 float4s) = 4 f2 pairs
  const float4* ip4 = reinterpret_cast<const float4*>(oin)
                      + (size_t)b * 48 * 65536 + tile*512 + t;
  const float4* pT4 = reinterpret_cast<const float4*>(prewT);
  f2 h0[8][4];
#pragma unroll
  for (int o = 0; o < 8; ++o) {
    float pb = preb[o];
#pragma unroll
    for (int p = 0; p < 4; ++p) h0[o][p] = (f2)pb;
  }
#pragma unroll 8
  for (int c = 0; c < 48; ++c) {
    float4 va = ip4[(size_t)c * 65536];
    float4 vb = ip4[(size_t)c * 65536 + 256];
    float2 ss = ssl[c];
    f2 g[4];
    g[0] = prelu(paff((f2){va.x, va.y}, ss.x, ss.y));
    g[1] = prelu(paff((f2){va.z, va.w}, ss.x, ss.y));
    g[2] = prelu(paff((f2){vb.x, vb.y}, ss.x, ss.y));
    g[3] = prelu(paff((f2){vb.z, vb.w}, ss.x, ss.y));
    float4 w0 = pT4[c*2], w1 = pT4[c*2+1];
    float wv[8] = {w0.x, w0.y, w0.z, w0.w, w1.x, w1.y, w1.z, w1.w};
#pragma unroll
    for (int o = 0; o < 8; ++o)
#pragma unroll
      for (int p = 0; p < 4; ++p) h0[o][p] = pfma(wv[o], g[p], h0[o][p]);
  }

  // per-class head; W read with wave-uniform indices (s_load path)
  const float* __restrict__ Wb = ws + WS_PAR + (size_t)b * NCLS * 153;
  float4* op4 = reinterpret_cast<float4*>(out)
                + (size_t)b * NCLS * 65536 + tile*512 + t;
#pragma unroll 1
  for (int cls = 0; cls < NCLS; ++cls) {
    const float* Wc = Wb + cls * 153;
    // layer1: t1 = relu(w1 @ h0 + b1)
    f2 t1[8][4];
#pragma unroll
    for (int i = 0; i < 8; ++i) {
      float bi = Wc[136 + i];
      f2 a[4];
#pragma unroll
      for (int p = 0; p < 4; ++p) a[p] = (f2)bi;
#pragma unroll
      for (int j = 0; j < 8; ++j) {
        float w = Wc[i*8 + j];
#pragma unroll
        for (int p = 0; p < 4; ++p) a[p] = pfma(w, h0[j][p], a[p]);
      }
#pragma unroll
      for (int p = 0; p < 4; ++p) t1[i][p] = prelu(a[p]);
    }
    // layer2 + layer3 fused (t2 row consumed immediately)
    float b3v = Wc[152];
    f2 lg[4];
#pragma unroll
    for (int p = 0; p < 4; ++p) lg[p] = (f2)b3v;
#pragma unroll
    for (int i = 0; i < 8; ++i) {
      float bi = Wc[144 + i];
      f2 a[4];
#pragma unroll
      for (int p = 0; p < 4; ++p) a[p] = (f2)bi;
#pragma unroll
      for (int j = 0; j < 8; ++j) {
        float w = Wc[64 + i*8 + j];
#pragma unroll
        for (int p = 0; p < 4; ++p) a[p] = pfma(w, t1[j][p], a[p]);
      }
      float w3 = Wc[128 + i];
#pragma unroll
      for (int p = 0; p < 4; ++p) {
        a[p] = prelu(a[p]);
        lg[p] = pfma(w3, a[p], lg[p]);
      }
    }
    op4[(size_t)cls * 65536]       = make_float4(lg[0].x, lg[0].y, lg[1].x, lg[1].y);
    op4[(size_t)cls * 65536 + 256] = make_float4(lg[2].x, lg[2].y, lg[3].x, lg[3].y);
  }
}

extern "C" void kernel_launch(void* const* d_in, const int* in_sizes, int n_in,
                              void* d_out, int out_size, void* d_ws, size_t ws_size,
                              hipStream_t stream) {
  const float* x    = (const float*)d_in[0];
  const float* oin  = (const float*)d_in[1];
  const float* te   = (const float*)d_in[2];
  const float* g1   = (const float*)d_in[3];
  const float* b1   = (const float*)d_in[4];
  const float* gapw = (const float*)d_in[5];
  const float* gapb = (const float*)d_in[6];
  const float* cw   = (const float*)d_in[7];
  const float* cb   = (const float*)d_in[8];
  const float* g2   = (const float*)d_in[9];
  const float* b2   = (const float*)d_in[10];
  const float* prew = (const float*)d_in[11];
  const float* preb = (const float*)d_in[12];
  float* ws  = (float*)d_ws;
  float* out = (float*)d_out;

  hipLaunchKernelGGL(k1_stats,  dim3(800),  dim3(256), 0, stream, x, oin, g1, b1, ws);
  hipLaunchKernelGGL(k2_xfeat,  dim3(128),  dim3(256), 0, stream, gapw, gapb, ws);
  hipLaunchKernelGGL(k3_params, dim3(2448), dim3(256), 0, stream, cw, cb, te, ws);
  hipLaunchKernelGGL(k4_main,   dim3(256),  dim3(256), 0, stream, oin, prew, preb, g2, b2, ws, out);
}

// Round 6
// 277.217 us; speedup vs baseline: 1.1012x; 1.1012x over previous
//
#include <hip/hip_runtime.h>

// x:    (2, 768, 8,8,8)   -> (2,768,512)
// out:  (2, 48, 64,64,64) -> (2,48,262144)
// output: (2, 32, 64,64,64)
constexpr int NCLS = 32;

// ws float offsets
constexpr int WS_POOL = 64;     // 2*768
constexpr int WS_XF  = 1600;    // 2*256
constexpr int WS_PAR = 2112;    // 2*32*153 = 9792
constexpr int WS_P2  = 11904;   // 768 blocks * {sum,sumsq}

typedef float f2 __attribute__((ext_vector_type(2)));
typedef float f4v __attribute__((ext_vector_type(4)));

__device__ __forceinline__ float wred(float v) {
#pragma unroll
  for (int off = 32; off > 0; off >>= 1) v += __shfl_down(v, off, 64);
  return v;
}

// packed fp32 helpers (v_pk_fma_f32: instr-count halved; cycle-rate = scalar fp32)
__device__ __forceinline__ f2 pfma(float w, f2 v, f2 a) {
  return __builtin_elementwise_fma((f2)w, v, a);
}
__device__ __forceinline__ f2 paff(f2 v, float sc, float sh) {
  return __builtin_elementwise_fma(v, (f2)sc, (f2)sh);
}
__device__ __forceinline__ f2 prelu(f2 a) {
  return __builtin_elementwise_max(a, (f2)0.f);
}

// K1: 800 blocks. Blocks 0..767: GN2 partial sums (32768 contiguous floats each).
//     Blocks 768..799: GN1 stats + relu-mean pool for one (b,group) (24576 floats).
__global__ void k1_stats(const float* __restrict__ x, const float* __restrict__ oin,
                         const float* __restrict__ g1, const float* __restrict__ b1,
                         float* __restrict__ ws) {
  int t = threadIdx.x;
  int wid = t >> 6, lane = t & 63;
  __shared__ float red[8];
  if (blockIdx.x < 768) {
    int blk = blockIdx.x;
    const float4* p = reinterpret_cast<const float4*>(oin + (size_t)blk * 32768);
    float s = 0.f, s2 = 0.f;
#pragma unroll
    for (int k = 0; k < 32; ++k) {
      float4 v = p[k * 256 + t];
      s  += v.x + v.y + v.z + v.w;
      s2 += v.x*v.x + v.y*v.y + v.z*v.z + v.w*v.w;
    }
    s = wred(s); s2 = wred(s2);
    if (lane == 0) { red[wid*2] = s; red[wid*2+1] = s2; }
    __syncthreads();
    if (t == 0) {
      ws[WS_P2 + blk*2]   = red[0]+red[2]+red[4]+red[6];
      ws[WS_P2 + blk*2+1] = red[1]+red[3]+red[5]+red[7];
    }
  } else {
    int g = blockIdx.x - 768;              // b = g>>4, grp = g&15
    __shared__ float mstat[2];
    const float4* p = reinterpret_cast<const float4*>(x + g * 24576);
    float s = 0.f, s2 = 0.f;
#pragma unroll
    for (int k = 0; k < 24; ++k) {
      float4 v = p[k * 256 + t];
      s  += v.x + v.y + v.z + v.w;
      s2 += v.x*v.x + v.y*v.y + v.z*v.z + v.w*v.w;
    }
    s = wred(s); s2 = wred(s2);
    if (lane == 0) { red[wid*2] = s; red[wid*2+1] = s2; }
    __syncthreads();
    if (t == 0) {
      float S  = red[0]+red[2]+red[4]+red[6];
      float S2 = red[1]+red[3]+red[5]+red[7];
      float mean = S * (1.f/24576.f);
      float var  = S2 * (1.f/24576.f) - mean*mean;
      mstat[0] = mean; mstat[1] = rsqrtf(var + 1e-5f);
    }
    __syncthreads();
    float mean = mstat[0], rstd = mstat[1];
#pragma unroll
    for (int k = 0; k < 12; ++k) {
      int i = k*4 + wid;                   // channel within group [0,48)
      int c = (g & 15) * 48 + i;           // channel [0,768)
      float sc = rstd * g1[c];
      float sh = b1[c] - mean * sc;
      const float* q = x + g * 24576 + i * 512;
      float acc = 0.f;
#pragma unroll
      for (int j = 0; j < 8; ++j)
        acc += fmaxf(fmaf(q[lane + j*64], sc, sh), 0.f);
      acc = wred(acc);
      if (lane == 0) ws[WS_POOL + (g >> 4) * 768 + c] = acc * (1.f/512.f);
    }
  }
}

// K2: x_feat, wave-per-output (coalesced row reads). 512 outputs -> 128 blocks.
__global__ void k2_xfeat(const float* __restrict__ gapw, const float* __restrict__ gapb,
                         float* __restrict__ ws) {
  int wid = threadIdx.x >> 6, lane = threadIdx.x & 63;
  int idx = blockIdx.x * 4 + wid;          // [0,512)
  int b = idx >> 8, o = idx & 255;
  const float* pw = gapw + o * 768;
  const float* pp = ws + WS_POOL + b * 768;
  float s = 0.f;
#pragma unroll
  for (int i = 0; i < 12; ++i) {
    int cc = lane + i*64;
    s += pw[cc] * pp[cc];
  }
  s = wred(s);
  if (lane == 0) ws[WS_XF + idx] = s + gapb[o];
}

// K3: params, wave-per-output (coalesced). 9792 outputs -> 2448 blocks.
// Writes params in K4's exact consumption order (stream layout):
//   np: for i in 0..8 -> {b1_i @ i*9, w1_i_j @ i*9+1+j}; b3 @ 72;
//       for i in 0..8 -> {b2_i @ 73+i*10, w2_i_j @ 73+i*10+1+j, w3_i @ 73+i*10+9}
// Monotonic s_load stream in K4 => minimal live-SGPR window, deep scalar pipelining.
__global__ void k3_params(const float* __restrict__ cw, const float* __restrict__ cb,
                          const float* __restrict__ te, float* __restrict__ ws) {
  int wid = threadIdx.x >> 6, lane = threadIdx.x & 63;
  int e = blockIdx.x * 4 + wid;            // [0,9792)
  int b = e / (NCLS * 153);
  int r = e % (NCLS * 153);
  int c = r / 153, p = r % 153;
  const float* w  = cw + p * 512;
  const float* xf = ws + WS_XF + b * 256;
  const float* tv = te + c * 256;
  float s = 0.f;
#pragma unroll
  for (int i = 0; i < 4; ++i) {
    int f = lane + i*64;
    s += w[f] * xf[f] + w[256 + f] * tv[f];
  }
  s = wred(s);
  if (lane == 0) {
    int np;
    if      (p < 64)  np = (p >> 3) * 9 + 1 + (p & 7);                       // w1
    else if (p < 128) { int i = (p - 64) >> 3; np = 73 + i*10 + 1 + ((p-64)&7); } // w2
    else if (p < 136) np = 73 + (p - 128) * 10 + 9;                          // w3
    else if (p < 144) np = (p - 136) * 9;                                    // b1
    else if (p < 152) np = 73 + (p - 144) * 10;                              // b2
    else              np = 72;                                               // b3
    ws[WS_PAR + (size_t)(b * NCLS + c) * 153 + np] = s + cb[p];
  }
}

// K4: fused GN2-finalize + main head. v6 (base = round-4 winner, 83us):
//  512 blocks x 256 thr; thread = 4 voxels; ALL 32 classes; SMEM weights.
//  Round-5 lesson: issue ~= 40us fixed; dur = issue/VALUBusy; VALUBusy tracks
//  stall-hiding. Stall = scattered s_load bursts per class with hard lgkm waits.
//  Fix: (a) stream-ordered weight layout (see K3), (b) unroll-2 class loop so
//  class c+1's s_loads overlap class c's ~600cyc of math, (c) nontemporal
//  stores keep 67MB of write-once output from evicting L3-resident oin.
__global__ __launch_bounds__(256) void k4_main(const float* __restrict__ oin,
                                               const float* __restrict__ prew,
                                               const float* __restrict__ preb,
                                               const float* __restrict__ g2,
                                               const float* __restrict__ b2,
                                               const float* __restrict__ ws,
                                               float* __restrict__ out) {
  __shared__ __align__(16) float prewT[384];
  __shared__ float2 ssl[48];
  __shared__ float ms[64];
  int t = threadIdx.x;
  int b    = blockIdx.x >> 8;        // batch [0,2)
  int tile = blockIdx.x & 255;       // [0,256) -> 1024 voxels per tile

  if (t < 32) {
    float S = 0.f, S2 = 0.f;
#pragma unroll
    for (int k = 0; k < 24; ++k) {
      S  += ws[WS_P2 + (t*24 + k)*2];
      S2 += ws[WS_P2 + (t*24 + k)*2 + 1];
    }
    float mean = S * (1.f/786432.f);
    float var  = S2 * (1.f/786432.f) - mean*mean;
    ms[t*2] = mean; ms[t*2+1] = rsqrtf(var + 1e-5f);
  }
  if (t < 128) {
#pragma unroll
    for (int k = 0; k < 3; ++k) {
      int i = t + k*128;
      prewT[(i % 48) * 8 + (i / 48)] = prew[i];
    }
  }
  __syncthreads();
  if (t < 48) {
    int grp = (b << 4) + t / 3;
    float mean = ms[grp*2], rstd = ms[grp*2+1];
    float sc = rstd * g2[t];
    ssl[t] = make_float2(sc, b2[t] - mean * sc);
  }
  __syncthreads();

  // h0 for 4 voxels (one float4 = 2 f2)
  const float4* ip4 = reinterpret_cast<const float4*>(oin)
                      + (size_t)b * 48 * 65536 + tile*256 + t;
  const float4* pT4 = reinterpret_cast<const float4*>(prewT);
  f2 h0[8][2];
#pragma unroll
  for (int o = 0; o < 8; ++o) {
    float pb = preb[o];
    h0[o][0] = (f2)pb; h0[o][1] = (f2)pb;
  }
#pragma unroll 8
  for (int c = 0; c < 48; ++c) {
    float4 v = ip4[(size_t)c * 65536];
    float2 ss = ssl[c];
    f2 g0 = prelu(paff((f2){v.x, v.y}, ss.x, ss.y));
    f2 g1 = prelu(paff((f2){v.z, v.w}, ss.x, ss.y));
    float4 w0 = pT4[c*2], w1 = pT4[c*2+1];
    float wv[8] = {w0.x, w0.y, w0.z, w0.w, w1.x, w1.y, w1.z, w1.w};
#pragma unroll
    for (int o = 0; o < 8; ++o) {
      h0[o][0] = pfma(wv[o], g0, h0[o][0]);
      h0[o][1] = pfma(wv[o], g1, h0[o][1]);
    }
  }

  // per-class head; W streamed with wave-uniform monotonic indices (s_load path)
  const float* __restrict__ Wb = ws + WS_PAR + (size_t)b * NCLS * 153;
  f4v* op4 = reinterpret_cast<f4v*>(out)
             + (size_t)b * NCLS * 65536 + tile*256 + t;
#pragma unroll 2
  for (int cls = 0; cls < NCLS; ++cls) {
    const float* Wc = Wb + cls * 153;
    // layer1: t1_i = relu(sum_j w1_ij h0_j + b1_i); stream {b1_i, w1_i*}
    f2 t1[8][2];
#pragma unroll
    for (int i = 0; i < 8; ++i) {
      const float* row = Wc + i * 9;
      float bi = row[0];
      f2 a0 = (f2)bi, a1 = (f2)bi;
#pragma unroll
      for (int j = 0; j < 8; ++j) {
        float w = row[1 + j];
        a0 = pfma(w, h0[j][0], a0);
        a1 = pfma(w, h0[j][1], a1);
      }
      t1[i][0] = prelu(a0); t1[i][1] = prelu(a1);
    }
    // layer2 + layer3 fused; stream {b3} then {b2_i, w2_i*, w3_i}
    float b3v = Wc[72];
    f2 lg0 = (f2)b3v, lg1 = (f2)b3v;
#pragma unroll
    for (int i = 0; i < 8; ++i) {
      const float* row = Wc + 73 + i * 10;
      float bi = row[0];
      f2 a0 = (f2)bi, a1 = (f2)bi;
#pragma unroll
      for (int j = 0; j < 8; ++j) {
        float w = row[1 + j];
        a0 = pfma(w, t1[j][0], a0);
        a1 = pfma(w, t1[j][1], a1);
      }
      a0 = prelu(a0); a1 = prelu(a1);
      float w3 = row[9];
      lg0 = pfma(w3, a0, lg0);
      lg1 = pfma(w3, a1, lg1);
    }
    __builtin_nontemporal_store((f4v){lg0.x, lg0.y, lg1.x, lg1.y},
                                op4 + (size_t)cls * 65536);
  }
}

extern "C" void kernel_launch(void* const* d_in, const int* in_sizes, int n_in,
                              void* d_out, int out_size, void* d_ws, size_t ws_size,
                              hipStream_t stream) {
  const float* x    = (const float*)d_in[0];
  const float* oin  = (const float*)d_in[1];
  const float* te   = (const float*)d_in[2];
  const float* g1   = (const float*)d_in[3];
  const float* b1   = (const float*)d_in[4];
  const float* gapw = (const float*)d_in[5];
  const float* gapb = (const float*)d_in[6];
  const float* cw   = (const float*)d_in[7];
  const float* cb   = (const float*)d_in[8];
  const float* g2   = (const float*)d_in[9];
  const float* b2   = (const float*)d_in[10];
  const float* prew = (const float*)d_in[11];
  const float* preb = (const float*)d_in[12];
  float* ws  = (float*)d_ws;
  float* out = (float*)d_out;

  hipLaunchKernelGGL(k1_stats,  dim3(800),  dim3(256), 0, stream, x, oin, g1, b1, ws);
  hipLaunchKernelGGL(k2_xfeat,  dim3(128),  dim3(256), 0, stream, gapw, gapb, ws);
  hipLaunchKernelGGL(k3_params, dim3(2448), dim3(256), 0, stream, cw, cb, te, ws);
  hipLaunchKernelGGL(k4_main,   dim3(512),  dim3(256), 0, stream, oin, prew, preb, g2, b2, ws, out);
}

// Round 7
// 271.764 us; speedup vs baseline: 1.1233x; 1.0201x over previous
//
#include <hip/hip_runtime.h>

// x:    (2, 768, 8,8,8)   -> (2,768,512)
// out:  (2, 48, 64,64,64) -> (2,48,262144)
// output: (2, 32, 64,64,64)
constexpr int NCLS = 32;

// ws float offsets
constexpr int WS_POOL = 64;     // 2*768
constexpr int WS_XF  = 1600;    // 2*256
constexpr int WS_PAR = 2112;    // 2*32*153 = 9792
constexpr int WS_P2  = 11904;   // 768 blocks * {sum,sumsq}

typedef float f2 __attribute__((ext_vector_type(2)));

__device__ __forceinline__ float wred(float v) {
#pragma unroll
  for (int off = 32; off > 0; off >>= 1) v += __shfl_down(v, off, 64);
  return v;
}

// packed fp32 helpers (v_pk_fma_f32: instr-count halved vs scalar)
__device__ __forceinline__ f2 pfma(float w, f2 v, f2 a) {
  return __builtin_elementwise_fma((f2)w, v, a);
}
__device__ __forceinline__ f2 paff(f2 v, float sc, float sh) {
  return __builtin_elementwise_fma(v, (f2)sc, (f2)sh);
}
__device__ __forceinline__ f2 prelu(f2 a) {
  return __builtin_elementwise_max(a, (f2)0.f);
}

// K1: 800 blocks. Blocks 0..767: GN2 partial sums (32768 contiguous floats each).
//     Blocks 768..799: GN1 stats + relu-mean pool for one (b,group) (24576 floats).
__global__ void k1_stats(const float* __restrict__ x, const float* __restrict__ oin,
                         const float* __restrict__ g1, const float* __restrict__ b1,
                         float* __restrict__ ws) {
  int t = threadIdx.x;
  int wid = t >> 6, lane = t & 63;
  __shared__ float red[8];
  if (blockIdx.x < 768) {
    int blk = blockIdx.x;
    const float4* p = reinterpret_cast<const float4*>(oin + (size_t)blk * 32768);
    float s = 0.f, s2 = 0.f;
#pragma unroll
    for (int k = 0; k < 32; ++k) {
      float4 v = p[k * 256 + t];
      s  += v.x + v.y + v.z + v.w;
      s2 += v.x*v.x + v.y*v.y + v.z*v.z + v.w*v.w;
    }
    s = wred(s); s2 = wred(s2);
    if (lane == 0) { red[wid*2] = s; red[wid*2+1] = s2; }
    __syncthreads();
    if (t == 0) {
      ws[WS_P2 + blk*2]   = red[0]+red[2]+red[4]+red[6];
      ws[WS_P2 + blk*2+1] = red[1]+red[3]+red[5]+red[7];
    }
  } else {
    int g = blockIdx.x - 768;              // b = g>>4, grp = g&15
    __shared__ float mstat[2];
    const float4* p = reinterpret_cast<const float4*>(x + g * 24576);
    float s = 0.f, s2 = 0.f;
#pragma unroll
    for (int k = 0; k < 24; ++k) {
      float4 v = p[k * 256 + t];
      s  += v.x + v.y + v.z + v.w;
      s2 += v.x*v.x + v.y*v.y + v.z*v.z + v.w*v.w;
    }
    s = wred(s); s2 = wred(s2);
    if (lane == 0) { red[wid*2] = s; red[wid*2+1] = s2; }
    __syncthreads();
    if (t == 0) {
      float S  = red[0]+red[2]+red[4]+red[6];
      float S2 = red[1]+red[3]+red[5]+red[7];
      float mean = S * (1.f/24576.f);
      float var  = S2 * (1.f/24576.f) - mean*mean;
      mstat[0] = mean; mstat[1] = rsqrtf(var + 1e-5f);
    }
    __syncthreads();
    float mean = mstat[0], rstd = mstat[1];
#pragma unroll
    for (int k = 0; k < 12; ++k) {
      int i = k*4 + wid;                   // channel within group [0,48)
      int c = (g & 15) * 48 + i;           // channel [0,768)
      float sc = rstd * g1[c];
      float sh = b1[c] - mean * sc;
      const float* q = x + g * 24576 + i * 512;
      float acc = 0.f;
#pragma unroll
      for (int j = 0; j < 8; ++j)
        acc += fmaxf(fmaf(q[lane + j*64], sc, sh), 0.f);
      acc = wred(acc);
      if (lane == 0) ws[WS_POOL + (g >> 4) * 768 + c] = acc * (1.f/512.f);
    }
  }
}

// K2: x_feat, wave-per-output (coalesced row reads). 512 outputs -> 128 blocks.
__global__ void k2_xfeat(const float* __restrict__ gapw, const float* __restrict__ gapb,
                         float* __restrict__ ws) {
  int wid = threadIdx.x >> 6, lane = threadIdx.x & 63;
  int idx = blockIdx.x * 4 + wid;          // [0,512)
  int b = idx >> 8, o = idx & 255;
  const float* pw = gapw + o * 768;
  const float* pp = ws + WS_POOL + b * 768;
  float s = 0.f;
#pragma unroll
  for (int i = 0; i < 12; ++i) {
    int cc = lane + i*64;
    s += pw[cc] * pp[cc];
  }
  s = wred(s);
  if (lane == 0) ws[WS_XF + idx] = s + gapb[o];
}

// K3: params, wave-per-output (coalesced). 9792 outputs -> 2448 blocks.
// Compact layout (round-4 proven): p order = reference param order.
__global__ void k3_params(const float* __restrict__ cw, const float* __restrict__ cb,
                          const float* __restrict__ te, float* __restrict__ ws) {
  int wid = threadIdx.x >> 6, lane = threadIdx.x & 63;
  int e = blockIdx.x * 4 + wid;            // [0,9792)
  int b = e / (NCLS * 153);
  int r = e % (NCLS * 153);
  int c = r / 153, p = r % 153;
  const float* w  = cw + p * 512;
  const float* xf = ws + WS_XF + b * 256;
  const float* tv = te + c * 256;
  float s = 0.f;
#pragma unroll
  for (int i = 0; i < 4; ++i) {
    int f = lane + i*64;
    s += w[f] * xf[f] + w[256 + f] * tv[f];
  }
  s = wred(s);
  if (lane == 0) ws[WS_PAR + e] = s + cb[p];
}

// K4: fused GN2-finalize + main head. v7 = round-4 base + LDS weights.
//  Stall model (r0/r3/r4/r5 fit): at iso-occupancy the LDS-broadcast weight
//  path exposes ~half the stall of the s_load path (43 vs 78 us @ 1 wave/SIMD)
//  because ds_reads pipeline under fine-grained lgkmcnt while s_load chains
//  serialize under SGPR pressure. This config = 4 vox/thread, ALL 32 classes,
//  pk math, 512 blocks (2 waves/SIMD), weights staged once in LDS (20.5 KB).
__global__ __launch_bounds__(256) void k4_main(const float* __restrict__ oin,
                                               const float* __restrict__ prew,
                                               const float* __restrict__ preb,
                                               const float* __restrict__ g2,
                                               const float* __restrict__ b2,
                                               const float* __restrict__ ws,
                                               float* __restrict__ out) {
  __shared__ __align__(16) float Wl[NCLS * 160];   // 32 classes, 160-float stride
  __shared__ __align__(16) float prewT[384];
  __shared__ float2 ssl[48];
  __shared__ float ms[64];
  int t = threadIdx.x;
  int b    = blockIdx.x >> 8;        // batch [0,2)
  int tile = blockIdx.x & 255;       // [0,256) -> 1024 voxels per tile

  if (t < 32) {
    float S = 0.f, S2 = 0.f;
#pragma unroll
    for (int k = 0; k < 24; ++k) {
      S  += ws[WS_P2 + (t*24 + k)*2];
      S2 += ws[WS_P2 + (t*24 + k)*2 + 1];
    }
    float mean = S * (1.f/786432.f);
    float var  = S2 * (1.f/786432.f) - mean*mean;
    ms[t*2] = mean; ms[t*2+1] = rsqrtf(var + 1e-5f);
  }
  if (t < 128) {
#pragma unroll
    for (int k = 0; k < 3; ++k) {
      int i = t + k*128;
      prewT[(i % 48) * 8 + (i / 48)] = prew[i];
    }
  }
  {
    const float* wsrc = ws + WS_PAR + (size_t)b * NCLS * 153;
#pragma unroll 4
    for (int cc = 0; cc < NCLS; ++cc)
      if (t < 153) Wl[cc*160 + t] = wsrc[cc*153 + t];
  }
  __syncthreads();
  if (t < 48) {
    int grp = (b << 4) + t / 3;
    float mean = ms[grp*2], rstd = ms[grp*2+1];
    float sc = rstd * g2[t];
    ssl[t] = make_float2(sc, b2[t] - mean * sc);
  }
  __syncthreads();

  // h0 for 4 voxels (one float4 = 2 f2)
  const float4* ip4 = reinterpret_cast<const float4*>(oin)
                      + (size_t)b * 48 * 65536 + tile*256 + t;
  const float4* pT4 = reinterpret_cast<const float4*>(prewT);
  f2 h0[8][2];
#pragma unroll
  for (int o = 0; o < 8; ++o) {
    float pb = preb[o];
    h0[o][0] = (f2)pb; h0[o][1] = (f2)pb;
  }
#pragma unroll 8
  for (int c = 0; c < 48; ++c) {
    float4 v = ip4[(size_t)c * 65536];
    float2 ss = ssl[c];
    f2 g0 = prelu(paff((f2){v.x, v.y}, ss.x, ss.y));
    f2 g1 = prelu(paff((f2){v.z, v.w}, ss.x, ss.y));
    float4 w0 = pT4[c*2], w1 = pT4[c*2+1];
    float wv[8] = {w0.x, w0.y, w0.z, w0.w, w1.x, w1.y, w1.z, w1.w};
#pragma unroll
    for (int o = 0; o < 8; ++o) {
      h0[o][0] = pfma(wv[o], g0, h0[o][0]);
      h0[o][1] = pfma(wv[o], g1, h0[o][1]);
    }
  }

  // per-class head; weights via LDS broadcast reads (ds_read pipelines under
  // fine-grained lgkmcnt; no SGPR-pressure serialization)
  float4* op4 = reinterpret_cast<float4*>(out)
                + (size_t)b * NCLS * 65536 + tile*256 + t;
#pragma unroll 1
  for (int cls = 0; cls < NCLS; ++cls) {
    const float* Wc = Wl + cls * 160;
    // layer1: t1 = relu(w1 @ h0 + b1)
    f2 t1[8][2];
#pragma unroll
    for (int i = 0; i < 8; ++i) {
      float bi = Wc[136 + i];
      f2 a0 = (f2)bi, a1 = (f2)bi;
#pragma unroll
      for (int j = 0; j < 8; ++j) {
        float w = Wc[i*8 + j];
        a0 = pfma(w, h0[j][0], a0);
        a1 = pfma(w, h0[j][1], a1);
      }
      t1[i][0] = prelu(a0); t1[i][1] = prelu(a1);
    }
    // layer2 + layer3 fused (t2 row consumed immediately)
    float b3v = Wc[152];
    f2 lg0 = (f2)b3v, lg1 = (f2)b3v;
#pragma unroll
    for (int i = 0; i < 8; ++i) {
      float bi = Wc[144 + i];
      f2 a0 = (f2)bi, a1 = (f2)bi;
#pragma unroll
      for (int j = 0; j < 8; ++j) {
        float w = Wc[64 + i*8 + j];
        a0 = pfma(w, t1[j][0], a0);
        a1 = pfma(w, t1[j][1], a1);
      }
      a0 = prelu(a0); a1 = prelu(a1);
      float w3 = Wc[128 + i];
      lg0 = pfma(w3, a0, lg0);
      lg1 = pfma(w3, a1, lg1);
    }
    op4[(size_t)cls * 65536] = make_float4(lg0.x, lg0.y, lg1.x, lg1.y);
  }
}

extern "C" void kernel_launch(void* const* d_in, const int* in_sizes, int n_in,
                              void* d_out, int out_size, void* d_ws, size_t ws_size,
                              hipStream_t stream) {
  const float* x    = (const float*)d_in[0];
  const float* oin  = (const float*)d_in[1];
  const float* te   = (const float*)d_in[2];
  const float* g1   = (const float*)d_in[3];
  const float* b1   = (const float*)d_in[4];
  const float* gapw = (const float*)d_in[5];
  const float* gapb = (const float*)d_in[6];
  const float* cw   = (const float*)d_in[7];
  const float* cb   = (const float*)d_in[8];
  const float* g2   = (const float*)d_in[9];
  const float* b2   = (const float*)d_in[10];
  const float* prew = (const float*)d_in[11];
  const float* preb = (const float*)d_in[12];
  float* ws  = (float*)d_ws;
  float* out = (float*)d_out;

  hipLaunchKernelGGL(k1_stats,  dim3(800),  dim3(256), 0, stream, x, oin, g1, b1, ws);
  hipLaunchKernelGGL(k2_xfeat,  dim3(128),  dim3(256), 0, stream, gapw, gapb, ws);
  hipLaunchKernelGGL(k3_params, dim3(2448), dim3(256), 0, stream, cw, cb, te, ws);
  hipLaunchKernelGGL(k4_main,   dim3(512),  dim3(256), 0, stream, oin, prew, preb, g2, b2, ws, out);
}